// Round 5
// baseline (202.227 us; speedup 1.0000x reference)
//
#include <hip/hip_runtime.h>

// CrossAttentionGAT — algebraically collapsed; edge path = block-local
// counting sort into coarse buckets (coalesced run writes) + per-lane-record
// LDS-privatized segment reduction (64 gathers in flight per instruction).
//
// mean(cross1) = mean(emb2) @ Wl + bl   (softmax col-sums == 1)
// mean(cross2) = mean(emb1) @ Wl + bl   (softmax row-sums == 1)
// mean(emb)    = (1/N) * sum_k g[head,k] * W[k, head*C+c] + b
//   g[head,k]  = sum_n w[n,head] x[n,k],  w[n,head] = sum_{e: src=n} alpha_e[head]

#define NN 8192
#define EE 262144
#define NEG 0.2f

#define BKT 128           // node buckets per graph
#define RNG (NN / BKT)    // 64 nodes per bucket
#define CAP 2560          // bucket capacity: mean 2048 + >10 sigma
#define EB  128           // bin blocks per graph
#define CHK (EE / EB)     // 2048 edges per bin block

// ---------------- ws layout (4-byte units) ----------------
#define U_CNT   0                        // 2 graphs x {D,S} x BKT ints (zeroed)
#define U_G     (U_CNT + 4*BKT)          // 2*1024 floats (zeroed)
#define U_MEMB  (U_G + 2048)             // 2*1024 floats (zeroed)
#define U_ZEND  (U_MEMB + 2048)
#define U_U     (U_ZEND)                 // 2*2048 floats
#define U_ASRC  (U_U + 2*2048)           // 2*NN*8 floats
#define U_ADST  (U_ASRC + 2*NN*8)        // 2*NN*8 floats
#define U_PR    (U_ADST + 2*NN*8)        // 2*NN*16 floats: (adst,rden) float2
#define U_WACC  (U_PR + 2*NN*16)         // 2*NN*8 floats
#define U_BIND  (U_WACC + 2*NN*8)        // 2*BKT*CAP ints
#define U_BINS  (U_BIND + 2*BKT*CAP)     // 2*BKT*CAP ints
#define ZERO_BYTES ((size_t)U_ZEND * 4)

// K1: u[graph][sd][head][k] = att[head][:] . W[k][head*128:+128]
__global__ __launch_bounds__(256) void k_u(
    const float* __restrict__ W1, const float* __restrict__ as1, const float* __restrict__ ad1,
    const float* __restrict__ W2, const float* __restrict__ as2, const float* __restrict__ ad2,
    float* __restrict__ u) {
  int b = blockIdx.x;                  // graph*16 + sd*8 + head
  int graph = b >> 4, sd = (b >> 3) & 1, head = b & 7;
  const float* W = graph ? W2 : W1;
  const float* att = graph ? (sd ? ad2 : as2) : (sd ? ad1 : as1);
  int w = threadIdx.x >> 6, lane = threadIdx.x & 63;
  float2 av = ((const float2*)(att + head * 128))[lane];
  float* uo = u + graph * 2048 + sd * 1024 + head * 128;
#pragma unroll 4
  for (int k = w; k < 128; k += 4) {
    float2 wv = ((const float2*)(W + (size_t)k * 1024 + head * 128))[lane];
    float p = av.x * wv.x + av.y * wv.y;
    p += __shfl_xor(p, 1);  p += __shfl_xor(p, 2);  p += __shfl_xor(p, 4);
    p += __shfl_xor(p, 8);  p += __shfl_xor(p, 16); p += __shfl_xor(p, 32);
    if (lane == 0) uo[k] = p;
  }
}

// K2: a_src[n,h] = x[n,:] . u_src[h,:] ; a_dst likewise. 64 nodes/block.
__global__ __launch_bounds__(256) void k_a(
    const float* __restrict__ x1, const float* __restrict__ x2,
    const float* __restrict__ u, float* __restrict__ asrc, float* __restrict__ adst) {
  int graph = blockIdx.y;
  const float* x = graph ? x2 : x1;
  const float* ug = u + graph * 2048;
  __shared__ float xs[64][129];
  __shared__ float us[16][128];
  int t = threadIdx.x;
  for (int i = t; i < 2048; i += 256) us[i >> 7][i & 127] = ug[i];
  int n0 = blockIdx.x * 64;
  const float* xb = x + (size_t)n0 * 128;
  for (int i = t; i < 64 * 128; i += 256) xs[i >> 7][i & 127] = xb[i];
  __syncthreads();
  int nl = t & 63;
  int j0 = (t >> 6) * 4;
  float a0 = 0.f, a1 = 0.f, a2 = 0.f, a3 = 0.f;
#pragma unroll 4
  for (int k = 0; k < 128; ++k) {
    float xv = xs[nl][k];
    a0 += xv * us[j0 + 0][k];
    a1 += xv * us[j0 + 1][k];
    a2 += xv * us[j0 + 2][k];
    a3 += xv * us[j0 + 3][k];
  }
  int n = n0 + nl;
  float* outp = (j0 < 8) ? (asrc + graph * (NN * 8) + n * 8 + j0)
                         : (adst + graph * (NN * 8) + n * 8 + (j0 - 8));
  outp[0] = a0; outp[1] = a1; outp[2] = a2; outp[3] = a3;
}

// K3: block-local counting sort of 2048 edges into 128 dst-buckets and 128
// src-buckets; coalesced contiguous run writes to global bins.
__global__ __launch_bounds__(512) void k_bin(
    const int* __restrict__ ei1, const int* __restrict__ ei2,
    int* __restrict__ cnt, int* __restrict__ binD, int* __restrict__ binS) {
  int g = blockIdx.y;
  const int* ei = g ? ei2 : ei1;
  __shared__ int hD[BKT], hS[BKT], scD[BKT], scS[BKT];
  __shared__ int cD[BKT], cS[BKT], bD[BKT], bS[BKT];
  __shared__ int ldsD[CHK], ldsS[CHK];
  __shared__ unsigned char kbAD[CHK], kbAS[CHK];
  int t = threadIdx.x;
  if (t < BKT) { hD[t] = 0; cD[t] = 0; }
  else if (t < 2 * BKT) { int i = t - BKT; hS[i] = 0; cS[i] = 0; }
  __syncthreads();
  int e0 = blockIdx.x * CHK;
  int sv[4], dv[4];
#pragma unroll
  for (int k = 0; k < 4; ++k) {
    sv[k] = ei[e0 + t + k * 512];
    dv[k] = ei[EE + e0 + t + k * 512];
    atomicAdd(&hD[dv[k] >> 6], 1);
    atomicAdd(&hS[sv[k] >> 6], 1);
  }
  __syncthreads();
  // reserve global space + init inclusive-scan source
  if (t < BKT) { scD[t] = hD[t]; bD[t] = atomicAdd(cnt + (2 * g + 0) * BKT + t, hD[t]); }
  else if (t < 2 * BKT) { int i = t - BKT; scS[i] = hS[i]; bS[i] = atomicAdd(cnt + (2 * g + 1) * BKT + i, hS[i]); }
  __syncthreads();
  // Hillis-Steele inclusive scan of scD (threads 0..127) and scS (128..255)
  for (int o = 1; o < BKT; o <<= 1) {
    int v = 0;
    if (t < BKT) { if (t >= o) v = scD[t - o]; }
    else if (t < 2 * BKT) { int i = t - BKT; if (i >= o) v = scS[i - o]; }
    __syncthreads();
    if (t < BKT) scD[t] += v;
    else if (t < 2 * BKT) scS[t - BKT] += v;
    __syncthreads();
  }
  // scatter into LDS-sorted order
#pragma unroll
  for (int k = 0; k < 4; ++k) {
    int kb = dv[k] >> 6;
    int pos = (scD[kb] - hD[kb]) + atomicAdd(&cD[kb], 1);
    ldsD[pos] = (sv[k] << 6) | (dv[k] & 63);
    kbAD[pos] = (unsigned char)kb;
    kb = sv[k] >> 6;
    pos = (scS[kb] - hS[kb]) + atomicAdd(&cS[kb], 1);
    ldsS[pos] = (dv[k] << 6) | (sv[k] & 63);
    kbAS[pos] = (unsigned char)kb;
  }
  __syncthreads();
  // coalesced run copy-out
  int* bdg = binD + (size_t)g * BKT * CAP;
  int* bsg = binS + (size_t)g * BKT * CAP;
#pragma unroll
  for (int k = 0; k < 4; ++k) {
    int i = t + k * 512;
    int kb = kbAD[i];
    bdg[kb * CAP + bD[kb] + (i - (scD[kb] - hD[kb]))] = ldsD[i];
    kb = kbAS[i];
    bsg[kb * CAP + bS[kb] + (i - (scS[kb] - hS[kb]))] = ldsS[i];
  }
}

// K4: per dst-bucket: den[h][dl] = selfloop + sum exp(lrelu(asrc[s]+adst[d])).
// One record per lane: 64 independent 32B gathers per load instruction.
__global__ __launch_bounds__(512) void k_den_red(
    const int* __restrict__ cnt, const int* __restrict__ binD,
    const float* __restrict__ asrc, const float* __restrict__ adst,
    float* __restrict__ pr) {
  int g = blockIdx.y, b = blockIdx.x;
  int lo = b * RNG;
  const float* as = asrc + g * (NN * 8);
  const float* ad = adst + g * (NN * 8);
  float2* prg = (float2*)pr + (size_t)g * (NN * 8);
  __shared__ float den[8][RNG];     // [h][dl]: per-instr banks spread ~32
  __shared__ float adsts[8][RNG];
  int t = threadIdx.x;
  { // tile init with self loop (s == d)
    int dl = t & 63, h = t >> 6;
    float avv = ad[(lo + dl) * 8 + h];
    float v = as[(lo + dl) * 8 + h] + avv;
    v = v > 0.f ? v : NEG * v;
    adsts[h][dl] = avv;
    den[h][dl] = __expf(v);
  }
  __syncthreads();
  int n = cnt[(2 * g + 0) * BKT + b];
  const int* recs = binD + (size_t)g * BKT * CAP + b * CAP;
  for (int base = 0; base < n; base += 2048) {
    int rv[4]; bool ok[4]; float4 q0[4], q1[4];
#pragma unroll
    for (int k = 0; k < 4; ++k) {
      int i = base + k * 512 + t;
      ok[k] = i < n;
      rv[k] = ok[k] ? recs[i] : 0;
    }
#pragma unroll
    for (int k = 0; k < 4; ++k) {
      const float4* p = (const float4*)(as + (size_t)(rv[k] >> 6) * 8);
      if (ok[k]) { q0[k] = p[0]; q1[k] = p[1]; }
    }
#pragma unroll
    for (int k = 0; k < 4; ++k) {
      if (ok[k]) {
        int dl = rv[k] & 63;
        float e[8] = {q0[k].x, q0[k].y, q0[k].z, q0[k].w,
                      q1[k].x, q1[k].y, q1[k].z, q1[k].w};
#pragma unroll
        for (int h = 0; h < 8; ++h) {
          float v = e[h] + adsts[h][dl];
          v = v > 0.f ? v : NEG * v;
          atomicAdd(&den[h][dl], __expf(v));
        }
      }
    }
  }
  __syncthreads();
  { // coalesced pr write: consecutive t -> consecutive (n,h)
    int dl = t >> 3, h = t & 7;
    prg[lo * 8 + t] = make_float2(adsts[h][dl], 1.0f / den[h][dl]);
  }
}

// K5: per src-bucket: w[h][sl] = selfloop + sum exp(lrelu(asrc[s]+adst[d]))*rden[d].
__global__ __launch_bounds__(512) void k_wacc_red(
    const int* __restrict__ cnt, const int* __restrict__ binS,
    const float* __restrict__ asrc, const float* __restrict__ pr,
    float* __restrict__ wacc) {
  int g = blockIdx.y, b = blockIdx.x;
  int lo = b * RNG;
  const float* as = asrc + g * (NN * 8);
  const float2* prg = (const float2*)pr + (size_t)g * (NN * 8);
  __shared__ float wv[8][RNG];
  __shared__ float asrcs[8][RNG];
  int t = threadIdx.x;
  { // tile init with self loop
    int sl = t & 63, h = t >> 6;
    float sva = as[(lo + sl) * 8 + h];
    float2 f2 = prg[(lo + sl) * 8 + h];
    float v = sva + f2.x;
    v = v > 0.f ? v : NEG * v;
    asrcs[h][sl] = sva;
    wv[h][sl] = __expf(v) * f2.y;
  }
  __syncthreads();
  int n = cnt[(2 * g + 1) * BKT + b];
  const int* recs = binS + (size_t)g * BKT * CAP + b * CAP;
  for (int base = 0; base < n; base += 2048) {
    int rv[4]; bool ok[4]; float4 q0[4], q1[4], q2[4], q3[4];
#pragma unroll
    for (int k = 0; k < 4; ++k) {
      int i = base + k * 512 + t;
      ok[k] = i < n;
      rv[k] = ok[k] ? recs[i] : 0;
    }
#pragma unroll
    for (int k = 0; k < 4; ++k) {
      const float4* p = (const float4*)(prg + (size_t)(rv[k] >> 6) * 8);
      if (ok[k]) { q0[k] = p[0]; q1[k] = p[1]; q2[k] = p[2]; q3[k] = p[3]; }
    }
#pragma unroll
    for (int k = 0; k < 4; ++k) {
      if (ok[k]) {
        int sl = rv[k] & 63;
        float a[8] = {q0[k].x, q0[k].z, q1[k].x, q1[k].z,
                      q2[k].x, q2[k].z, q3[k].x, q3[k].z};
        float r[8] = {q0[k].y, q0[k].w, q1[k].y, q1[k].w,
                      q2[k].y, q2[k].w, q3[k].y, q3[k].w};
#pragma unroll
        for (int h = 0; h < 8; ++h) {
          float v = asrcs[h][sl] + a[h];
          v = v > 0.f ? v : NEG * v;
          atomicAdd(&wv[h][sl], __expf(v) * r[h]);
        }
      }
    }
  }
  __syncthreads();
  { // coalesced wacc write
    int sl = t >> 3, h = t & 7;
    wacc[g * (NN * 8) + lo * 8 + t] = wv[h][sl];
  }
}

// K6: g[head,k] = sum_n w[n,head] * x[n,k].
#define GCHUNK 256
__global__ __launch_bounds__(256) void k_gred(
    const float* __restrict__ x1, const float* __restrict__ x2,
    const float* __restrict__ wacc, float* __restrict__ g) {
  int graph = blockIdx.y;
  const float* x = graph ? x2 : x1;
  const float* w = wacc + graph * (NN * 8);
  float* gg = g + graph * 1024;
  int t = threadIdx.x;
  int k = t & 127;
  int h0 = (t >> 7) * 4;
  int n0 = blockIdx.x * GCHUNK;
  float a0 = 0.f, a1 = 0.f, a2 = 0.f, a3 = 0.f;
#pragma unroll 4
  for (int n = n0; n < n0 + GCHUNK; ++n) {
    float xv = x[(size_t)n * 128 + k];
    float4 wv4 = *(const float4*)(w + (size_t)n * 8 + h0);
    a0 += xv * wv4.x; a1 += xv * wv4.y; a2 += xv * wv4.z; a3 += xv * wv4.w;
  }
  atomicAdd(gg + (h0 + 0) * 128 + k, a0);
  atomicAdd(gg + (h0 + 1) * 128 + k, a1);
  atomicAdd(gg + (h0 + 2) * 128 + k, a2);
  atomicAdd(gg + (h0 + 3) * 128 + k, a3);
}

// K7: memb[graph][e] += (1/N) * sum_{k chunk} g[head,k]*W[k*1024+e] (+b at kc=0)
__global__ __launch_bounds__(256) void k_memb(
    const float* __restrict__ W1, const float* __restrict__ W2,
    const float* __restrict__ b1, const float* __restrict__ b2,
    const float* __restrict__ g, float* __restrict__ memb) {
  int graph = blockIdx.z;
  int kc = blockIdx.y;
  const float* W = graph ? W2 : W1;
  const float* b = graph ? b2 : b1;
  int e = blockIdx.x * 256 + threadIdx.x;
  int head = e >> 7;
  const float* gr = g + graph * 1024 + head * 128;
  float s = 0.f;
#pragma unroll
  for (int k = kc * 16; k < kc * 16 + 16; ++k) s += gr[k] * W[(size_t)k * 1024 + e];
  s *= (1.0f / (float)NN);
  if (kc == 0) s += b[e];
  atomicAdd(memb + graph * 1024 + e, s);
}

// K8: out = [memb(g1); memb(g0)] @ Wl + bl, split-k over 32 blocks (out zeroed).
__global__ __launch_bounds__(256) void k_out(
    const float* __restrict__ memb, const float* __restrict__ Wl,
    const float* __restrict__ bl, float* __restrict__ out) {
  int t = threadIdx.x;
  int j = t & 127;
  int k0 = blockIdx.x * 32;
  const float* m = (t < 128) ? (memb + 1024) : memb;
  float s = 0.f;
#pragma unroll
  for (int k = k0; k < k0 + 32; ++k) s += m[k] * Wl[(size_t)k * 128 + j];
  if (blockIdx.x == 0) s += bl[j];
  atomicAdd(out + t, s);
}

extern "C" void kernel_launch(void* const* d_in, const int* in_sizes, int n_in,
                              void* d_out, int out_size, void* d_ws, size_t ws_size,
                              hipStream_t stream) {
  const float* x1  = (const float*)d_in[0];
  const int*   ei1 = (const int*)d_in[1];
  const float* W1  = (const float*)d_in[2];
  const float* as1 = (const float*)d_in[3];
  const float* ad1 = (const float*)d_in[4];
  const float* b1  = (const float*)d_in[5];
  const float* x2  = (const float*)d_in[6];
  const int*   ei2 = (const int*)d_in[7];
  const float* W2  = (const float*)d_in[8];
  const float* as2 = (const float*)d_in[9];
  const float* ad2 = (const float*)d_in[10];
  const float* b2  = (const float*)d_in[11];
  const float* Wl  = (const float*)d_in[12];
  const float* bl  = (const float*)d_in[13];
  float* out = (float*)d_out;

  int*   cnt  = (int*)d_ws + U_CNT;
  float* g    = (float*)d_ws + U_G;
  float* memb = (float*)d_ws + U_MEMB;
  float* u    = (float*)d_ws + U_U;
  float* asrc = (float*)d_ws + U_ASRC;
  float* adst = (float*)d_ws + U_ADST;
  float* pr   = (float*)d_ws + U_PR;
  float* wacc = (float*)d_ws + U_WACC;
  int*   binD = (int*)d_ws + U_BIND;
  int*   binS = (int*)d_ws + U_BINS;

  hipMemsetAsync(d_ws, 0, ZERO_BYTES, stream);             // cnt + g + memb
  hipMemsetAsync(d_out, 0, (size_t)out_size * 4, stream);  // split-k target

  k_bin<<<dim3(EB, 2), 512, 0, stream>>>(ei1, ei2, cnt, binD, binS);
  k_u<<<32, 256, 0, stream>>>(W1, as1, ad1, W2, as2, ad2, u);
  k_a<<<dim3(NN / 64, 2), 256, 0, stream>>>(x1, x2, u, asrc, adst);
  k_den_red<<<dim3(BKT, 2), 512, 0, stream>>>(cnt, binD, asrc, adst, pr);
  k_wacc_red<<<dim3(BKT, 2), 512, 0, stream>>>(cnt, binS, asrc, pr, wacc);
  k_gred<<<dim3(NN / GCHUNK, 2), 256, 0, stream>>>(x1, x2, wacc, g);
  k_memb<<<dim3(4, 8, 2), 256, 0, stream>>>(W1, W2, b1, b2, g, memb);
  k_out<<<32, 256, 0, stream>>>(memb, Wl, bl, out);
}